// Round 4
// baseline (192.946 us; speedup 1.0000x reference)
//
#include <hip/hip_runtime.h>

#define N_NODES 2048
#define IN_DIM 128
#define HID 64
#define N_EDGES 32768
#define EPS 1e-5f
#define MAX_TILES 4608

typedef short short8 __attribute__((ext_vector_type(8)));
typedef float f32x4 __attribute__((ext_vector_type(4)));

__device__ __forceinline__ float relu_f(float x) { return fmaxf(x, 0.f); }

__device__ __forceinline__ unsigned short f2bf(float f) {
  unsigned int u = __float_as_uint(f);
  u = (u + 0x7fffu + ((u >> 16) & 1u)) >> 16;   // RNE
  return (unsigned short)u;
}
__device__ __forceinline__ float bf2f(unsigned short h) {
  return __uint_as_float(((unsigned int)h) << 16);
}
__device__ __forceinline__ short8 pack8(const float* f) {
  short8 o;
  #pragma unroll
  for (int i = 0; i < 8; ++i) o[i] = (short)f2bf(f[i]);
  return o;
}

// ============ fused prep: h->bf16 | W2^T/W3^T bf16 | W1^T bf16 | LN->bf16 | p2 ============
__global__ __launch_bounds__(256) void prep_all(
    const float* __restrict__ h, const float* __restrict__ W2,
    const float* __restrict__ W3, const float* __restrict__ W1,
    const float* __restrict__ local, const float* __restrict__ ln_w,
    const float* __restrict__ ln_b, const float* __restrict__ Wp2,
    const float* __restrict__ bp2,
    unsigned short* __restrict__ hb, unsigned short* __restrict__ w2tb,
    unsigned short* __restrict__ w3tb, unsigned short* __restrict__ w1t,
    unsigned short* __restrict__ lnlb, unsigned short* __restrict__ p2b)
{
  __shared__ float tile[32][33];
  __shared__ float hs[4][IN_DIM];
  const int b = blockIdx.x, t = threadIdx.x;

  if (b < 256) {                       // cast h: 2048*128 elements
    int idx = (b * 256 + t) * 4;
    float4 v = *(const float4*)(h + idx);
    ushort4 o; o.x = f2bf(v.x); o.y = f2bf(v.y); o.z = f2bf(v.z); o.w = f2bf(v.w);
    *(ushort4*)(hb + idx) = o;
  } else if (b == 256) {               // w2tb[j][x] = bf16(W2[x][j])
    for (int i = t; i < IN_DIM * HID; i += 256) {
      int x = i >> 6, j = i & 63;
      w2tb[j * IN_DIM + x] = f2bf(W2[i]);
    }
  } else if (b == 257) {               // w3tb[j][k] = bf16(W3[k][j])
    for (int i = t; i < HID * HID; i += 256) {
      int k = i >> 6, j = i & 63;
      w3tb[j * HID + k] = f2bf(W3[i]);
    }
  } else if (b < 258 + 512) {          // transpose W1 -> w1t [4096][128] bf16
    int b2 = b - 258;
    int n0 = (b2 & 127) * 32, k0 = (b2 >> 7) * 32;
    int tx = t & 31, ty = t >> 5;
    #pragma unroll
    for (int r = 0; r < 4; ++r)
      tile[ty + 8 * r][tx] = W1[(size_t)(k0 + ty + 8 * r) * 4096 + n0 + tx];
    __syncthreads();
    #pragma unroll
    for (int r = 0; r < 4; ++r)
      w1t[(size_t)(n0 + ty + 8 * r) * 128 + k0 + tx] = f2bf(tile[tx][ty + 8 * r]);
  } else if (b < 770 + 512) {          // LayerNorm rows -> bf16
    int wave = t >> 6, lane = t & 63;
    int row = (b - 770) * 4 + wave;
    const float* x = local + (size_t)row * IN_DIM;
    float x0 = x[lane], x1 = x[lane + 64];
    float s1 = x0 + x1, s2 = x0 * x0 + x1 * x1;
    #pragma unroll
    for (int off = 32; off > 0; off >>= 1) {
      s1 += __shfl_xor(s1, off);
      s2 += __shfl_xor(s2, off);
    }
    float mean = s1 * (1.f / IN_DIM);
    float var = s2 * (1.f / IN_DIM) - mean * mean;
    float rstd = rsqrtf(var + EPS);
    unsigned short* o = lnlb + (size_t)row * IN_DIM;
    o[lane]      = f2bf((x0 - mean) * rstd * ln_w[lane] + ln_b[lane]);
    o[lane + 64] = f2bf((x1 - mean) * rstd * ln_w[lane + 64] + ln_b[lane + 64]);
  } else {                             // p2 = relu(h @ Wp2 + bp2) -> bf16
    int wv = t >> 6, l = t & 63;
    int i = (b - 1282) * 4 + wv;
    hs[wv][l] = h[(size_t)i * IN_DIM + l];
    hs[wv][l + 64] = h[(size_t)i * IN_DIM + 64 + l];
    float acc = bp2[l];
    #pragma unroll 8
    for (int m = 0; m < IN_DIM; ++m) acc += hs[wv][m] * Wp2[m * HID + l];
    p2b[(size_t)i * HID + l] = f2bf(relu_f(acc));
  }
}

// ============ p1 = relu(h @ W1 + b1), bf16 MFMA, 64x128 tile, contiguous stores ============
__global__ __launch_bounds__(256) void p1_gemm(
    const unsigned short* __restrict__ hb,   // [2048][128]
    const unsigned short* __restrict__ w1t,  // [4096][128]
    const float* __restrict__ b1,
    unsigned short* __restrict__ p1b)        // [2048][4096]
{
  const int t = threadIdx.x;
  const int w = t >> 6, l = t & 63;
  const int lr = l & 15, lq = l >> 4;
  const int bm = (blockIdx.x & 31) * 64;
  const int bn = (blockIdx.x >> 5) * 128;
  const int m0 = bm + w * 16;

  f32x4 acc[8];
  #pragma unroll
  for (int ni = 0; ni < 8; ++ni) acc[ni] = (f32x4){0.f, 0.f, 0.f, 0.f};

  #pragma unroll
  for (int k0 = 0; k0 < 128; k0 += 32) {
    short8 bmf = *(const short8*)(hb + (size_t)(m0 + lr) * 128 + k0 + lq * 8);
    #pragma unroll
    for (int ni = 0; ni < 8; ++ni) {
      short8 a = *(const short8*)(w1t + (size_t)(bn + ni * 16 + lr) * 128 + k0 + lq * 8);
      // a (w1t rows = n) -> D reg rows; bmf (hb rows = m) -> D cols
      acc[ni] = __builtin_amdgcn_mfma_f32_16x16x32_bf16(a, bmf, acc[ni], 0, 0, 0);
    }
  }
  const int m = m0 + lr;
  #pragma unroll
  for (int ni = 0; ni < 8; ++ni) {
    int n = bn + ni * 16 + lq * 4;
    float4 bv = *(const float4*)&b1[n];
    ushort4 o;
    o.x = f2bf(relu_f(acc[ni][0] + bv.x));
    o.y = f2bf(relu_f(acc[ni][1] + bv.y));
    o.z = f2bf(relu_f(acc[ni][2] + bv.z));
    o.w = f2bf(relu_f(acc[ni][3] + bv.w));
    *(ushort4*)&p1b[(size_t)m * 4096 + n] = o;
  }
}

// ============ counting sort (direct padded scatter) ============
__global__ void hist_kernel(const int* __restrict__ src, int* __restrict__ cnt) {
  int e = blockIdx.x * 256 + threadIdx.x;
  atomicAdd(&cnt[src[e]], 1);
}

__global__ __launch_bounds__(256) void scan_kernel(
    const int* __restrict__ cnt, int* __restrict__ ptile, int* __restrict__ tile_src)
{
  __shared__ int part2[256];
  int t = threadIdx.x;
  int locT[8];
  int s2 = 0;
  #pragma unroll
  for (int i = 0; i < 8; ++i) {
    locT[i] = s2;
    s2 += (cnt[t * 8 + i] + 15) >> 4;
  }
  part2[t] = s2;
  __syncthreads();
  for (int off = 1; off < 256; off <<= 1) {
    int v = (t >= off) ? part2[t - off] : 0;
    __syncthreads();
    part2[t] += v;
    __syncthreads();
  }
  int base2 = (t == 0) ? 0 : part2[t - 1];
  #pragma unroll
  for (int i = 0; i < 8; ++i) {
    int node = t * 8 + i;
    int tb = base2 + locT[i];
    ptile[node] = tb;
    int nt = (cnt[node] + 15) >> 4;
    for (int k = 0; k < nt; ++k) tile_src[tb + k] = node;
  }
  if (t == 255) ptile[N_NODES] = part2[255];
}

__global__ void scatter_kernel(const int* __restrict__ src, const int* __restrict__ ptile,
                               int* __restrict__ cursor, int* __restrict__ perm_padded) {
  int e = blockIdx.x * 256 + threadIdx.x;
  int s = src[e];
  int r = atomicAdd(&cursor[s], 1);
  perm_padded[ptile[s] * 16 + r] = e;
}

// ============ fused edge kernel: one wave per 16-edge tile, both branches ============
__global__ __launch_bounds__(256) void edge_mfma(
    const unsigned short* __restrict__ p1b, const unsigned short* __restrict__ p2b,
    const unsigned short* __restrict__ lnlb,
    const int* __restrict__ dst, const int* __restrict__ perm_padded,
    const int* __restrict__ tile_src, const int* __restrict__ ptile,
    const unsigned short* __restrict__ w2tb, const unsigned short* __restrict__ w3tb,
    const float* __restrict__ conv_w, const float* __restrict__ conv_b,
    const float* __restrict__ b2, const float* __restrict__ b3,
    const float* __restrict__ bng_g, const float* __restrict__ bng_b,
    const float* __restrict__ bnG_g, const float* __restrict__ bnG_b,
    const float* __restrict__ bnL_g, const float* __restrict__ bnL_b,
    const float* __restrict__ e_in, float* __restrict__ out)
{
  __shared__ float gs[4][16][68];                // per-wave transpose buffer
  __shared__ unsigned short ln1s[4][16][136];    // per-wave dst LN rows (bf16)
  __shared__ unsigned short ln0s[4][136];        // per-wave src LN row  (bf16)

  const int t = threadIdx.x;
  const int w = t >> 6, l = t & 63;
  const int lr = l & 15, lq = l >> 4;
  const int n_tiles = ptile[N_NODES];
  const float rs = rsqrtf(1.f + EPS);

  float bngG[4], bngB[4], bnGG[4], bnGB[4], b3c[4], bnLG[4], bnLB[4], b2c[4];
  #pragma unroll
  for (int ni = 0; ni < 4; ++ni) {
    int col = ni * 16 + lr;
    bngG[ni] = bng_g[col] * rs; bngB[ni] = bng_b[col];
    bnGG[ni] = bnG_g[col] * rs; bnGB[ni] = bnG_b[col];
    bnLG[ni] = bnL_g[col] * rs; bnLB[ni] = bnL_b[col];
    b3c[ni] = b3[col]; b2c[ni] = b2[col];
  }
  const float cw0 = conv_w[0], cw1 = conv_w[1], cw2 = conv_w[2];
  const float cw3 = conv_w[3], cw4 = conv_w[4], cw5 = conv_w[5];
  const float cb = conv_b[0];

  for (int tile = blockIdx.x * 4 + w; tile < n_tiles; tile += gridDim.x * 4) {
    const int srcn = tile_src[tile];
    const int eidx = perm_padded[tile * 16 + lr];
    const int dn = (eidx >= 0) ? dst[eidx] : 0;

    // ---- stage LN rows (overlaps with global-branch compute) ----
    {
      const unsigned short* r1 = lnlb + (size_t)dn * IN_DIM + lq * 32;
      #pragma unroll
      for (int c2 = 0; c2 < 4; ++c2)
        *(uint4*)&ln1s[w][lr][lq * 32 + c2 * 8] = *(const uint4*)(r1 + c2 * 8);
      if (l < 32)
        *(ushort4*)&ln0s[w][l * 4] = *(const ushort4*)(lnlb + (size_t)srcn * IN_DIM + l * 4);
    }

    // ---- global branch: g = p2[dst] @ p1[src]^T ----
    const unsigned short* p2r = p2b + (size_t)dn * HID + lq * 8;
    short8 a0 = *(const short8*)(p2r);
    short8 a1 = *(const short8*)(p2r + 32);
    const unsigned short* pr = p1b + (size_t)srcn * 4096 + lr * 64 + lq * 8;
    f32x4 c[4];
    #pragma unroll
    for (int ni = 0; ni < 4; ++ni) {
      c[ni] = (f32x4){0.f, 0.f, 0.f, 0.f};
      short8 pb0 = *(const short8*)(pr + ni * 1024);
      short8 pb1 = *(const short8*)(pr + ni * 1024 + 32);
      c[ni] = __builtin_amdgcn_mfma_f32_16x16x32_bf16(a0, pb0, c[ni], 0, 0, 0);
      c[ni] = __builtin_amdgcn_mfma_f32_16x16x32_bf16(a1, pb1, c[ni], 0, 0, 0);
    }

    // bng + transpose (C rows=edges -> A rows=edges) through per-wave LDS
    #pragma unroll
    for (int ni = 0; ni < 4; ++ni)
      #pragma unroll
      for (int r = 0; r < 4; ++r)
        gs[w][lq * 4 + r][ni * 16 + lr] = c[ni][r] * bngG[ni] + bngB[ni];
    asm volatile("s_waitcnt lgkmcnt(0)" ::: "memory");
    short8 ga0 = pack8(&gs[w][lr][lq * 8]);
    short8 ga1 = pack8(&gs[w][lr][32 + lq * 8]);

    const unsigned short* wr3 = w3tb + lr * HID + lq * 8;
    f32x4 u[4];
    #pragma unroll
    for (int ni = 0; ni < 4; ++ni) {
      u[ni] = (f32x4){0.f, 0.f, 0.f, 0.f};
      short8 wb0 = *(const short8*)(wr3 + ni * 1024);
      short8 wb1 = *(const short8*)(wr3 + ni * 1024 + 32);
      u[ni] = __builtin_amdgcn_mfma_f32_16x16x32_bf16(ga0, wb0, u[ni], 0, 0, 0);
      u[ni] = __builtin_amdgcn_mfma_f32_16x16x32_bf16(ga1, wb1, u[ni], 0, 0, 0);
    }

    // ---- local branch: conv over staged LN rows -> A-frags -> @W2 ----
    asm volatile("s_waitcnt vmcnt(0) lgkmcnt(0)" ::: "memory");
    f32x4 v[4];
    #pragma unroll
    for (int ni = 0; ni < 4; ++ni) v[ni] = (f32x4){0.f, 0.f, 0.f, 0.f};
    #pragma unroll
    for (int ks = 0; ks < 4; ++ks) {
      short8 af;
      #pragma unroll
      for (int j = 0; j < 8; ++j) {
        int x = ks * 32 + lq * 8 + j;
        float am = (x > 0)   ? bf2f(ln0s[w][x - 1]) : 0.f;
        float az = bf2f(ln0s[w][x]);
        float ap = (x < 127) ? bf2f(ln0s[w][x + 1]) : 0.f;
        float bm = (x > 0)   ? bf2f(ln1s[w][lr][x - 1]) : 0.f;
        float bz = bf2f(ln1s[w][lr][x]);
        float bp = (x < 127) ? bf2f(ln1s[w][lr][x + 1]) : 0.f;
        float cv = relu_f(cw0 * am + cw1 * az + cw2 * ap +
                          cw3 * bm + cw4 * bz + cw5 * bp + cb);
        af[j] = (short)f2bf(cv);
      }
      #pragma unroll
      for (int ni = 0; ni < 4; ++ni) {
        short8 wb = *(const short8*)(w2tb + (size_t)(ni * 16 + lr) * IN_DIM + ks * 32 + lq * 8);
        v[ni] = __builtin_amdgcn_mfma_f32_16x16x32_bf16(af, wb, v[ni], 0, 0, 0);
      }
    }

    // ---- combine + store ----
    int er[4];
    #pragma unroll
    for (int r = 0; r < 4; ++r) er[r] = __shfl(eidx, lq * 4 + r);
    #pragma unroll
    for (int ni = 0; ni < 4; ++ni) {
      int col = ni * 16 + lr;
      #pragma unroll
      for (int r = 0; r < 4; ++r) {
        int e = er[r];
        if (e >= 0) {
          float vg = relu_f((u[ni][r] + b3c[ni]) * bnGG[ni] + bnGB[ni]);
          float vl = relu_f((v[ni][r] + b2c[ni]) * bnLG[ni] + bnLB[ni]);
          out[(size_t)e * HID + col] = vl + vg + e_in[(size_t)e * HID + col];
        }
      }
    }
  }
}

extern "C" void kernel_launch(void* const* d_in, const int* in_sizes, int n_in,
                              void* d_out, int out_size, void* d_ws, size_t ws_size,
                              hipStream_t stream) {
  const float* h      = (const float*)d_in[0];
  const float* local  = (const float*)d_in[1];
  const float* e_in   = (const float*)d_in[2];
  const int*   src    = (const int*)d_in[3];
  const int*   dst    = (const int*)d_in[4];
  const float* ln_w   = (const float*)d_in[5];
  const float* ln_b   = (const float*)d_in[6];
  const float* conv_w = (const float*)d_in[7];
  const float* conv_b = (const float*)d_in[8];
  const float* W1     = (const float*)d_in[9];
  const float* b1     = (const float*)d_in[10];
  const float* Wp2    = (const float*)d_in[11];
  const float* bp2    = (const float*)d_in[12];
  const float* W2     = (const float*)d_in[13];
  const float* b2     = (const float*)d_in[14];
  const float* W3     = (const float*)d_in[15];
  const float* b3     = (const float*)d_in[16];
  const float* bng_g  = (const float*)d_in[17];
  const float* bng_b  = (const float*)d_in[18];
  const float* bnG_g  = (const float*)d_in[19];
  const float* bnG_b  = (const float*)d_in[20];
  const float* bnL_g  = (const float*)d_in[21];
  const float* bnL_b  = (const float*)d_in[22];
  float* out = (float*)d_out;

  // ---- workspace layout ----
  char* p = (char*)d_ws;
  unsigned short* p1b  = (unsigned short*)p; p += (size_t)N_NODES * HID * HID * 2; // 16.78 MB
  unsigned short* p2b  = (unsigned short*)p; p += (size_t)N_NODES * HID * 2;
  unsigned short* lnlb = (unsigned short*)p; p += (size_t)N_NODES * IN_DIM * 2;
  unsigned short* hb   = (unsigned short*)p; p += (size_t)N_NODES * IN_DIM * 2;
  unsigned short* w1t  = (unsigned short*)p; p += (size_t)4096 * 128 * 2;
  unsigned short* w2tb = (unsigned short*)p; p += (size_t)HID * IN_DIM * 2;
  unsigned short* w3tb = (unsigned short*)p; p += (size_t)HID * HID * 2;
  int* cnt    = (int*)p; p += N_NODES * 4;
  int* cursor = (int*)p; p += N_NODES * 4;        // contiguous with cnt: one memset
  int* ptile  = (int*)p; p += (N_NODES + 1) * 4;
  int* tile_src    = (int*)p; p += MAX_TILES * 4;
  int* perm_padded = (int*)p; p += (size_t)MAX_TILES * 16 * 4;

  hipMemsetAsync(cnt, 0, 2 * N_NODES * sizeof(int), stream);                 // cnt + cursor
  hipMemsetAsync(perm_padded, 0xFF, (size_t)MAX_TILES * 16 * sizeof(int), stream);

  prep_all<<<1794, 256, 0, stream>>>(h, W2, W3, W1, local, ln_w, ln_b, Wp2, bp2,
                                     hb, w2tb, w3tb, w1t, lnlb, p2b);
  hist_kernel<<<N_EDGES / 256, 256, 0, stream>>>(src, cnt);
  p1_gemm<<<1024, 256, 0, stream>>>(hb, w1t, b1, p1b);
  scan_kernel<<<1, 256, 0, stream>>>(cnt, ptile, tile_src);
  scatter_kernel<<<N_EDGES / 256, 256, 0, stream>>>(src, ptile, cursor, perm_padded);
  edge_mfma<<<768, 256, 0, stream>>>(p1b, p2b, lnlb, dst, perm_padded, tile_src, ptile,
                                     w2tb, w3tb, conv_w, conv_b, b2, b3,
                                     bng_g, bng_b, bnG_g, bnG_b, bnL_g, bnL_b, e_in, out);
}

// Round 6
// 172.991 us; speedup vs baseline: 1.1154x; 1.1154x over previous
//
#include <hip/hip_runtime.h>

#define N_NODES 2048
#define IN_DIM 128
#define HID 64
#define N_EDGES 32768
#define EPS 1e-5f
#define MAX_TILES 4608

typedef short short8 __attribute__((ext_vector_type(8)));
typedef float f32x4 __attribute__((ext_vector_type(4)));

__device__ __forceinline__ float relu_f(float x) { return fmaxf(x, 0.f); }

__device__ __forceinline__ unsigned short f2bf(float f) {
  unsigned int u = __float_as_uint(f);
  u = (u + 0x7fffu + ((u >> 16) & 1u)) >> 16;   // RNE
  return (unsigned short)u;
}
__device__ __forceinline__ float bf2f(unsigned short h) {
  return __uint_as_float(((unsigned int)h) << 16);
}
__device__ __forceinline__ short8 pack8(const float* f) {
  short8 o;
  #pragma unroll
  for (int i = 0; i < 8; ++i) o[i] = (short)f2bf(f[i]);
  return o;
}

// ============ K1: prep (casts, LN, p2, W1^T) + histogram ============
__global__ __launch_bounds__(256) void prep_hist(
    const float* __restrict__ h, const float* __restrict__ local,
    const float* __restrict__ ln_w, const float* __restrict__ ln_b,
    const float* __restrict__ Wp2, const float* __restrict__ bp2,
    const float* __restrict__ W1, const float* __restrict__ W2,
    const float* __restrict__ W3, const int* __restrict__ src,
    unsigned short* __restrict__ hb, unsigned short* __restrict__ lnlb,
    unsigned short* __restrict__ p2b, unsigned short* __restrict__ w1t,
    unsigned short* __restrict__ w2tb, unsigned short* __restrict__ w3tb,
    int* __restrict__ cnt, int* __restrict__ perm_padded)
{
  __shared__ __align__(16) union {
    struct { float tile[IN_DIM][65]; } tr;
    struct { float hs[4][IN_DIM]; } p2s;
  } S;
  const int b = blockIdx.x, t = threadIdx.x;
  const int w = t >> 6, l = t & 63;

  if (b < 128) {
    // h -> bf16 (8 elems/thread) + perm_padded = -1
    int base = b * 2048 + t * 8;
    float4 v0 = *(const float4*)(h + base);
    float4 v1 = *(const float4*)(h + base + 4);
    ushort4 o0, o1;
    o0.x = f2bf(v0.x); o0.y = f2bf(v0.y); o0.z = f2bf(v0.z); o0.w = f2bf(v0.w);
    o1.x = f2bf(v1.x); o1.y = f2bf(v1.y); o1.z = f2bf(v1.z); o1.w = f2bf(v1.w);
    *(ushort4*)(hb + base) = o0;
    *(ushort4*)(hb + base + 4) = o1;
    int pbase = b * 576 + t;                     // 128*576 = MAX_TILES*16
    perm_padded[pbase] = -1;
    perm_padded[pbase + 256] = -1;
    if (t < 64) perm_padded[pbase + 512] = -1;
  } else if (b < 256) {
    // LayerNorm: 16 rows/block
    int nb = b - 128;
    #pragma unroll
    for (int i = 0; i < 4; ++i) {
      int row = nb * 16 + w * 4 + i;
      const float* x = local + (size_t)row * IN_DIM;
      float x0 = x[l], x1 = x[l + 64];
      float s1 = x0 + x1, s2 = x0 * x0 + x1 * x1;
      #pragma unroll
      for (int off = 32; off > 0; off >>= 1) {
        s1 += __shfl_xor(s1, off);
        s2 += __shfl_xor(s2, off);
      }
      float mean = s1 * (1.f / IN_DIM);
      float var = s2 * (1.f / IN_DIM) - mean * mean;
      float rstd = rsqrtf(var + EPS);
      unsigned short* o = lnlb + (size_t)row * IN_DIM;
      o[l]      = f2bf((x0 - mean) * rstd * ln_w[l] + ln_b[l]);
      o[l + 64] = f2bf((x1 - mean) * rstd * ln_w[l + 64] + ln_b[l + 64]);
    }
    if (b == 128) {
      for (int i = t; i < IN_DIM * HID; i += 256) {
        int x = i >> 6, j = i & 63;
        w2tb[j * IN_DIM + x] = f2bf(W2[i]);
      }
    } else if (b == 129) {
      for (int i = t; i < HID * HID; i += 256) {
        int k = i >> 6, j = i & 63;
        w3tb[j * HID + k] = f2bf(W3[i]);
      }
    }
  } else if (b < 384) {
    // p2 = relu(h @ Wp2 + bp2): 16 rows/block
    int pb = b - 256;
    #pragma unroll
    for (int i = 0; i < 4; ++i) {
      int row = pb * 16 + w * 4 + i;
      S.p2s.hs[w][l] = h[(size_t)row * IN_DIM + l];
      S.p2s.hs[w][l + 64] = h[(size_t)row * IN_DIM + 64 + l];
      float acc = bp2[l];
      #pragma unroll 8
      for (int m = 0; m < IN_DIM; ++m) acc += S.p2s.hs[w][m] * Wp2[m * HID + l];
      p2b[(size_t)row * HID + l] = f2bf(relu_f(acc));
    }
  } else if (b < 448) {
    // W1 [128,4096] -> w1t [4096,128] bf16, 64 n-cols/block
    int n0 = (b - 384) * 64;
    int tx = t & 63, ty = t >> 6;
    #pragma unroll
    for (int r = 0; r < 32; ++r) {
      int k = r * 4 + ty;
      S.tr.tile[k][tx] = W1[(size_t)k * 4096 + n0 + tx];
    }
    __syncthreads();
    int j = t >> 2, kb = (t & 3) * 32;
    #pragma unroll
    for (int c = 0; c < 8; ++c) {
      ushort4 o;
      o.x = f2bf(S.tr.tile[kb + c * 4 + 0][j]);
      o.y = f2bf(S.tr.tile[kb + c * 4 + 1][j]);
      o.z = f2bf(S.tr.tile[kb + c * 4 + 2][j]);
      o.w = f2bf(S.tr.tile[kb + c * 4 + 3][j]);
      *(ushort4*)&w1t[(size_t)(n0 + j) * 128 + kb + c * 4] = o;
    }
  } else {
    // histogram: 512 edges/block
    int e0 = (b - 448) * 512 + t;
    atomicAdd(&cnt[src[e0]], 1);
    atomicAdd(&cnt[src[e0 + 256]], 1);
  }
}

// ============ K2: p1 GEMM (blocks 0..1023) | scan+scatter (blocks 1024..1151) ============
__global__ __launch_bounds__(256) void gemm_scan(
    const unsigned short* __restrict__ hb, const unsigned short* __restrict__ w1t,
    const float* __restrict__ b1, unsigned short* __restrict__ p1b,
    const int* __restrict__ src, const int* __restrict__ cnt,
    int* __restrict__ cursor, int* __restrict__ ptile,
    int* __restrict__ tile_src, int* __restrict__ perm_padded)
{
  __shared__ __align__(16) struct { int part[256]; int pt[N_NODES]; } S;
  const int b = blockIdx.x, t = threadIdx.x;
  const int w = t >> 6, l = t & 63;
  const int lr = l & 15, lq = l >> 4;

  if (b < 1024) {
    const int bm = (b & 31) * 64;
    const int bn = (b >> 5) * 128;
    const int m0 = bm + w * 16;
    f32x4 acc[8];
    #pragma unroll
    for (int ni = 0; ni < 8; ++ni) acc[ni] = (f32x4){0.f, 0.f, 0.f, 0.f};
    #pragma unroll
    for (int k0 = 0; k0 < 128; k0 += 32) {
      short8 bmf = *(const short8*)(hb + (size_t)(m0 + lr) * 128 + k0 + lq * 8);
      #pragma unroll
      for (int ni = 0; ni < 8; ++ni) {
        short8 a = *(const short8*)(w1t + (size_t)(bn + ni * 16 + lr) * 128 + k0 + lq * 8);
        acc[ni] = __builtin_amdgcn_mfma_f32_16x16x32_bf16(a, bmf, acc[ni], 0, 0, 0);
      }
    }
    const int m = m0 + lr;
    #pragma unroll
    for (int ni = 0; ni < 8; ++ni) {
      int n = bn + ni * 16 + lq * 4;
      float4 bv = *(const float4*)&b1[n];
      ushort4 o;
      o.x = f2bf(relu_f(acc[ni][0] + bv.x));
      o.y = f2bf(relu_f(acc[ni][1] + bv.y));
      o.z = f2bf(relu_f(acc[ni][2] + bv.z));
      o.w = f2bf(relu_f(acc[ni][3] + bv.w));
      *(ushort4*)&p1b[(size_t)m * 4096 + n] = o;
    }
  } else {
    // redundant full scan in LDS, then scatter this block's 256-edge slice
    int nb = b - 1024;
    int locT[8];
    int s2 = 0;
    #pragma unroll
    for (int i = 0; i < 8; ++i) {
      locT[i] = s2;
      s2 += (cnt[t * 8 + i] + 15) >> 4;
    }
    S.part[t] = s2;
    __syncthreads();
    for (int off = 1; off < 256; off <<= 1) {
      int v = (t >= off) ? S.part[t - off] : 0;
      __syncthreads();
      S.part[t] += v;
      __syncthreads();
    }
    int base2 = (t == 0) ? 0 : S.part[t - 1];
    #pragma unroll
    for (int i = 0; i < 8; ++i) S.pt[t * 8 + i] = base2 + locT[i];
    if (nb == 0) {
      #pragma unroll
      for (int i = 0; i < 8; ++i) ptile[t * 8 + i] = base2 + locT[i];
      if (t == 255) ptile[N_NODES] = S.part[255];
    }
    __syncthreads();
    if (t < 16) {
      int node = nb * 16 + t;
      int base = S.pt[node];
      int nt = (cnt[node] + 15) >> 4;
      for (int k = 0; k < nt; ++k) tile_src[base + k] = node;
    }
    int e = nb * 256 + t;
    int s = src[e];
    int r = atomicAdd(&cursor[s], 1);
    perm_padded[S.pt[s] * 16 + r] = e;
  }
}

// ============ K3: fused edge kernel, one wave per 16-edge tile ============
__global__ __launch_bounds__(256) void edge_mfma(
    const unsigned short* __restrict__ p1b, const unsigned short* __restrict__ p2b,
    const unsigned short* __restrict__ lnlb,
    const int* __restrict__ dst, const int* __restrict__ perm_padded,
    const int* __restrict__ tile_src, const int* __restrict__ ptile,
    const unsigned short* __restrict__ w2tb, const unsigned short* __restrict__ w3tb,
    const float* __restrict__ conv_w, const float* __restrict__ conv_b,
    const float* __restrict__ b2, const float* __restrict__ b3,
    const float* __restrict__ bng_g, const float* __restrict__ bng_b,
    const float* __restrict__ bnG_g, const float* __restrict__ bnG_b,
    const float* __restrict__ bnL_g, const float* __restrict__ bnL_b,
    const float* __restrict__ e_in, float* __restrict__ out)
{
  __shared__ float gs[4][16][68];
  __shared__ unsigned short ln1s[4][16][136];
  __shared__ unsigned short ln0s[4][136];

  const int t = threadIdx.x;
  const int w = t >> 6, l = t & 63;
  const int lr = l & 15, lq = l >> 4;
  const int n_tiles = ptile[N_NODES];
  const float rs = rsqrtf(1.f + EPS);

  float bngG[4], bngB[4], bnGG[4], bnGB[4], b3c[4], bnLG[4], bnLB[4], b2c[4];
  #pragma unroll
  for (int ni = 0; ni < 4; ++ni) {
    int col = ni * 16 + lr;
    bngG[ni] = bng_g[col] * rs; bngB[ni] = bng_b[col];
    bnGG[ni] = bnG_g[col] * rs; bnGB[ni] = bnG_b[col];
    bnLG[ni] = bnL_g[col] * rs; bnLB[ni] = bnL_b[col];
    b3c[ni] = b3[col]; b2c[ni] = b2[col];
  }
  const float cw0 = conv_w[0], cw1 = conv_w[1], cw2 = conv_w[2];
  const float cw3 = conv_w[3], cw4 = conv_w[4], cw5 = conv_w[5];
  const float cb = conv_b[0];

  for (int tile = blockIdx.x * 4 + w; tile < n_tiles; tile += gridDim.x * 4) {
    const int srcn = tile_src[tile];
    const int eidx = perm_padded[tile * 16 + lr];
    const int dn = (eidx >= 0) ? dst[eidx] : 0;

    // stage LN rows
    {
      const unsigned short* r1 = lnlb + (size_t)dn * IN_DIM + lq * 32;
      #pragma unroll
      for (int c2 = 0; c2 < 4; ++c2)
        *(uint4*)&ln1s[w][lr][lq * 32 + c2 * 8] = *(const uint4*)(r1 + c2 * 8);
      if (l < 32)
        *(ushort4*)&ln0s[w][l * 4] = *(const ushort4*)(lnlb + (size_t)srcn * IN_DIM + l * 4);
    }

    // global branch: g = p2[dst] @ p1[src]^T
    const unsigned short* p2r = p2b + (size_t)dn * HID + lq * 8;
    short8 a0 = *(const short8*)(p2r);
    short8 a1 = *(const short8*)(p2r + 32);
    const unsigned short* pr = p1b + (size_t)srcn * 4096 + lr * 64 + lq * 8;
    f32x4 c[4];
    #pragma unroll
    for (int ni = 0; ni < 4; ++ni) {
      c[ni] = (f32x4){0.f, 0.f, 0.f, 0.f};
      short8 pb0 = *(const short8*)(pr + ni * 1024);
      short8 pb1 = *(const short8*)(pr + ni * 1024 + 32);
      c[ni] = __builtin_amdgcn_mfma_f32_16x16x32_bf16(a0, pb0, c[ni], 0, 0, 0);
      c[ni] = __builtin_amdgcn_mfma_f32_16x16x32_bf16(a1, pb1, c[ni], 0, 0, 0);
    }

    // bng + edge-axis transpose through per-wave LDS
    #pragma unroll
    for (int ni = 0; ni < 4; ++ni)
      #pragma unroll
      for (int r = 0; r < 4; ++r)
        gs[w][lq * 4 + r][ni * 16 + lr] = c[ni][r] * bngG[ni] + bngB[ni];
    asm volatile("s_waitcnt lgkmcnt(0)" ::: "memory");
    short8 ga0 = pack8(&gs[w][lr][lq * 8]);
    short8 ga1 = pack8(&gs[w][lr][32 + lq * 8]);

    const unsigned short* wr3 = w3tb + lr * HID + lq * 8;
    f32x4 u[4];
    #pragma unroll
    for (int ni = 0; ni < 4; ++ni) {
      u[ni] = (f32x4){0.f, 0.f, 0.f, 0.f};
      short8 wb0 = *(const short8*)(wr3 + ni * 1024);
      short8 wb1 = *(const short8*)(wr3 + ni * 1024 + 32);
      u[ni] = __builtin_amdgcn_mfma_f32_16x16x32_bf16(ga0, wb0, u[ni], 0, 0, 0);
      u[ni] = __builtin_amdgcn_mfma_f32_16x16x32_bf16(ga1, wb1, u[ni], 0, 0, 0);
    }

    // local branch: conv -> A-frags -> @W2
    asm volatile("s_waitcnt vmcnt(0) lgkmcnt(0)" ::: "memory");
    f32x4 v[4];
    #pragma unroll
    for (int ni = 0; ni < 4; ++ni) v[ni] = (f32x4){0.f, 0.f, 0.f, 0.f};
    #pragma unroll
    for (int ks = 0; ks < 4; ++ks) {
      short8 af;
      #pragma unroll
      for (int j = 0; j < 8; ++j) {
        int x = ks * 32 + lq * 8 + j;
        float am = (x > 0)   ? bf2f(ln0s[w][x - 1]) : 0.f;
        float az = bf2f(ln0s[w][x]);
        float ap = (x < 127) ? bf2f(ln0s[w][x + 1]) : 0.f;
        float bm = (x > 0)   ? bf2f(ln1s[w][lr][x - 1]) : 0.f;
        float bz = bf2f(ln1s[w][lr][x]);
        float bp = (x < 127) ? bf2f(ln1s[w][lr][x + 1]) : 0.f;
        float cv = relu_f(cw0 * am + cw1 * az + cw2 * ap +
                          cw3 * bm + cw4 * bz + cw5 * bp + cb);
        af[j] = (short)f2bf(cv);
      }
      #pragma unroll
      for (int ni = 0; ni < 4; ++ni) {
        short8 wb = *(const short8*)(w2tb + (size_t)(ni * 16 + lr) * IN_DIM + ks * 32 + lq * 8);
        v[ni] = __builtin_amdgcn_mfma_f32_16x16x32_bf16(af, wb, v[ni], 0, 0, 0);
      }
    }

    // combine + store
    int er[4];
    #pragma unroll
    for (int r = 0; r < 4; ++r) er[r] = __shfl(eidx, lq * 4 + r);
    #pragma unroll
    for (int ni = 0; ni < 4; ++ni) {
      int col = ni * 16 + lr;
      #pragma unroll
      for (int r = 0; r < 4; ++r) {
        int e = er[r];
        if (e >= 0) {
          float vg = relu_f((u[ni][r] + b3c[ni]) * bnGG[ni] + bnGB[ni]);
          float vl = relu_f((v[ni][r] + b2c[ni]) * bnLG[ni] + bnLB[ni]);
          out[(size_t)e * HID + col] = vl + vg + e_in[(size_t)e * HID + col];
        }
      }
    }
  }
}

extern "C" void kernel_launch(void* const* d_in, const int* in_sizes, int n_in,
                              void* d_out, int out_size, void* d_ws, size_t ws_size,
                              hipStream_t stream) {
  const float* h      = (const float*)d_in[0];
  const float* local  = (const float*)d_in[1];
  const float* e_in   = (const float*)d_in[2];
  const int*   src    = (const int*)d_in[3];
  const int*   dst    = (const int*)d_in[4];
  const float* ln_w   = (const float*)d_in[5];
  const float* ln_b   = (const float*)d_in[6];
  const float* conv_w = (const float*)d_in[7];
  const float* conv_b = (const float*)d_in[8];
  const float* W1     = (const float*)d_in[9];
  const float* b1     = (const float*)d_in[10];
  const float* Wp2    = (const float*)d_in[11];
  const float* bp2    = (const float*)d_in[12];
  const float* W2     = (const float*)d_in[13];
  const float* b2     = (const float*)d_in[14];
  const float* W3     = (const float*)d_in[15];
  const float* b3     = (const float*)d_in[16];
  const float* bng_g  = (const float*)d_in[17];
  const float* bng_b  = (const float*)d_in[18];
  const float* bnG_g  = (const float*)d_in[19];
  const float* bnG_b  = (const float*)d_in[20];
  const float* bnL_g  = (const float*)d_in[21];
  const float* bnL_b  = (const float*)d_in[22];
  float* out = (float*)d_out;

  char* p = (char*)d_ws;
  unsigned short* p1b  = (unsigned short*)p; p += (size_t)N_NODES * HID * HID * 2; // 16.78 MB
  unsigned short* p2b  = (unsigned short*)p; p += (size_t)N_NODES * HID * 2;
  unsigned short* lnlb = (unsigned short*)p; p += (size_t)N_NODES * IN_DIM * 2;
  unsigned short* hb   = (unsigned short*)p; p += (size_t)N_NODES * IN_DIM * 2;
  unsigned short* w1t  = (unsigned short*)p; p += (size_t)4096 * 128 * 2;
  unsigned short* w2tb = (unsigned short*)p; p += (size_t)HID * IN_DIM * 2;
  unsigned short* w3tb = (unsigned short*)p; p += (size_t)HID * HID * 2;
  int* cnt    = (int*)p; p += N_NODES * 4;
  int* cursor = (int*)p; p += N_NODES * 4;       // contiguous with cnt: one memset
  int* ptile  = (int*)p; p += (N_NODES + 1) * 4;
  int* tile_src    = (int*)p; p += MAX_TILES * 4;
  int* perm_padded = (int*)p; p += (size_t)MAX_TILES * 16 * 4;

  hipMemsetAsync(cnt, 0, 2 * N_NODES * sizeof(int), stream);   // cnt + cursor

  prep_hist<<<512, 256, 0, stream>>>(h, local, ln_w, ln_b, Wp2, bp2, W1, W2, W3, src,
                                     hb, lnlb, p2b, w1t, w2tb, w3tb, cnt, perm_padded);
  gemm_scan<<<1152, 256, 0, stream>>>(hb, w1t, b1, p1b, src, cnt, cursor,
                                      ptile, tile_src, perm_padded);
  edge_mfma<<<1024, 256, 0, stream>>>(p1b, p2b, lnlb, dst, perm_padded, tile_src, ptile,
                                      w2tb, w3tb, conv_w, conv_b, b2, b3,
                                      bng_g, bng_b, bnG_g, bnG_b, bnL_g, bnL_b, e_in, out);
}